// Round 19
// baseline (29321.973 us; speedup 1.0000x reference)
//
#include <hip/hip_runtime.h>

#define B 8
#define D 512
#define T 2048
#define K 8192
#define M (B*T)

typedef float f32x4 __attribute__((ext_vector_type(4)));
typedef int   i32x4 __attribute__((ext_vector_type(4)));
typedef char  c16   __attribute__((ext_vector_type(16)));
typedef unsigned short us8 __attribute__((ext_vector_type(8)));

#define CAP_SEG 48          // per-y-segment candidate cap (4 segs x 48 = 192)
#define WIN 1.3e-2f         // i8 path: 2*delta <= 1.2e-2 (rigorous bound)

// ws layout (bytes)
#define WS_X2    0                  // f32[M]      65536
#define WS_E2    65536              // f32[K]      32768
#define WS_CNT   98304              // u8[M*4]     65536 (segment counts)
#define WS_IDS   163840             // i32[M]      65536
#define WS_OVFC  229376             // i32
#define WS_XMAX  229380             // u32 (ord-encoded |x| max)
#define WS_OVFL  229632             // i32[M]      65536
#define WS_BEST  295168             // u64[M]      131072
#define WS_GMIN  426240             // u32[M]      65536
#define WS_LIST  491776             // u16[M*192]  6291456
#define WS_AX    6783232            // i8[M*512]   8388608 (was bf16)
#define WS_BE    23560448           // i8[K*512]   4194304 (was bf16)
#define WS_NEED  31949056

// order-preserving f32 <-> u32 (no NaNs in data)
__device__ inline unsigned int f2ord(float f) {
    unsigned int u = __float_as_uint(f);
    return (u & 0x80000000u) ? ~u : (u | 0x80000000u);
}
__device__ inline float ord2f(unsigned int u) {
    return __uint_as_float((u & 0x80000000u) ? (u & 0x7fffffffu) : ~u);
}

__device__ inline void gload16(const void* g, void* l) {
    __builtin_amdgcn_global_load_lds(
        (const __attribute__((address_space(1))) unsigned int*)g,
        (__attribute__((address_space(3))) unsigned int*)l, 16, 0, 0);
}

// ---- x2 + init + absmax: numpy-pairwise x2 (VALIDATED r3) ----------------
__global__ __launch_bounds__(256)
void vq_x2_init(const float* __restrict__ lat, float* __restrict__ x2g,
                unsigned int* __restrict__ cnt_seg_u32, int* __restrict__ ovfc,
                unsigned int* __restrict__ gmin, unsigned int* __restrict__ gmax) {
#pragma clang fp contract(off)
    int p = blockIdx.x * 256 + threadIdx.x;
    cnt_seg_u32[p] = 0;
    gmin[p] = 0xFFFFFFFFu;
    if (p == 0) *ovfc = 0;
    int b = p / T, t = p % T;
    const float* base = lat + (size_t)b * D * T + t;
    float blk[4];
    float amax = 0.f;
#pragma unroll
    for (int q = 0; q < 4; q++) {
        float r[8];
#pragma unroll
        for (int j = 0; j < 8; j++) {
            float v = base[(size_t)(q * 128 + j) * T];
            amax = fmaxf(amax, fabsf(v));
            r[j] = __fmul_rn(v, v);
        }
        for (int i = 8; i < 128; i += 8) {
#pragma unroll
            for (int j = 0; j < 8; j++) {
                float v = base[(size_t)(q * 128 + i + j) * T];
                amax = fmaxf(amax, fabsf(v));
                r[j] = __fadd_rn(r[j], __fmul_rn(v, v));
            }
        }
        blk[q] = __fadd_rn(__fadd_rn(__fadd_rn(r[0], r[1]), __fadd_rn(r[2], r[3])),
                           __fadd_rn(__fadd_rn(r[4], r[5]), __fadd_rn(r[6], r[7])));
    }
    x2g[p] = __fadd_rn(__fadd_rn(blk[0], blk[1]), __fadd_rn(blk[2], blk[3]));
    // wave-reduce absmax, one atomic per wave (ord-encoded; poison 0xAA.. is tiny)
#pragma unroll
    for (int off = 32; off; off >>= 1)
        amax = fmaxf(amax, __shfl_xor(amax, off));
    if ((threadIdx.x & 63) == 0) atomicMax(gmax, f2ord(amax));
}

// ---- x2 plain (small-ws fallback path) -----------------------------------
__global__ __launch_bounds__(256)
void vq_x2_kernel(const float* __restrict__ lat, float* __restrict__ x2g) {
#pragma clang fp contract(off)
    int p = blockIdx.x * 256 + threadIdx.x;
    int b = p / T, t = p % T;
    const float* base = lat + (size_t)b * D * T + t;
    float blk[4];
#pragma unroll
    for (int q = 0; q < 4; q++) {
        float r[8];
#pragma unroll
        for (int j = 0; j < 8; j++) {
            float v = base[(size_t)(q * 128 + j) * T];
            r[j] = __fmul_rn(v, v);
        }
        for (int i = 8; i < 128; i += 8) {
#pragma unroll
            for (int j = 0; j < 8; j++) {
                float v = base[(size_t)(q * 128 + i + j) * T];
                r[j] = __fadd_rn(r[j], __fmul_rn(v, v));
            }
        }
        blk[q] = __fadd_rn(__fadd_rn(__fadd_rn(r[0], r[1]), __fadd_rn(r[2], r[3])),
                           __fadd_rn(__fadd_rn(r[4], r[5]), __fadd_rn(r[6], r[7])));
    }
    x2g[p] = __fadd_rn(__fadd_rn(blk[0], blk[1]), __fadd_rn(blk[2], blk[3]));
}

// ---- e2[k]: numpy-pairwise tree, float4 loads (VALIDATED r13) ------------
__global__ __launch_bounds__(256)
void vq_e2_kernel(const float* __restrict__ emb, float* __restrict__ e2g) {
#pragma clang fp contract(off)
    int k = blockIdx.x * 256 + threadIdx.x;
    const float* base = emb + (size_t)k * D;
    float blk[4];
#pragma unroll
    for (int q = 0; q < 4; q++) {
        float r[8];
        {
            float4 a = *(const float4*)&base[q * 128];
            float4 c = *(const float4*)&base[q * 128 + 4];
            r[0] = __fmul_rn(a.x, a.x); r[1] = __fmul_rn(a.y, a.y);
            r[2] = __fmul_rn(a.z, a.z); r[3] = __fmul_rn(a.w, a.w);
            r[4] = __fmul_rn(c.x, c.x); r[5] = __fmul_rn(c.y, c.y);
            r[6] = __fmul_rn(c.z, c.z); r[7] = __fmul_rn(c.w, c.w);
        }
        for (int i = 8; i < 128; i += 8) {
            float4 a = *(const float4*)&base[q * 128 + i];
            float4 c = *(const float4*)&base[q * 128 + i + 4];
            r[0] = __fadd_rn(r[0], __fmul_rn(a.x, a.x));
            r[1] = __fadd_rn(r[1], __fmul_rn(a.y, a.y));
            r[2] = __fadd_rn(r[2], __fmul_rn(a.z, a.z));
            r[3] = __fadd_rn(r[3], __fmul_rn(a.w, a.w));
            r[4] = __fadd_rn(r[4], __fmul_rn(c.x, c.x));
            r[5] = __fadd_rn(r[5], __fmul_rn(c.y, c.y));
            r[6] = __fadd_rn(r[6], __fmul_rn(c.z, c.z));
            r[7] = __fadd_rn(r[7], __fmul_rn(c.w, c.w));
        }
        blk[q] = __fadd_rn(__fadd_rn(__fadd_rn(r[0], r[1]), __fadd_rn(r[2], r[3])),
                           __fadd_rn(__fadd_rn(r[4], r[5]), __fadd_rn(r[6], r[7])));
    }
    e2g[k] = __fadd_rn(__fadd_rn(blk[0], blk[1]), __fadd_rn(blk[2], blk[3]));
}

// ---- prep A: Ax[m][d] = i8 quantized latents (scale = xmax/127) ----------
__global__ __launch_bounds__(256)
void vq_prep_a(const float* __restrict__ lat, signed char* __restrict__ Ax,
               const unsigned int* __restrict__ gmax) {
    __shared__ float xsl[64][65];
    const int tid = threadIdx.x;
    const int m0 = blockIdx.x * 64;
    const int b = m0 / T, t0 = m0 % T;
    const float* lp = lat + (size_t)b * D * T + t0;
    const float inv_sx = 127.0f / ord2f(*gmax);
    for (int d0 = 0; d0 < D; d0 += 64) {
        if (d0) __syncthreads();
#pragma unroll
        for (int i = 0; i < 16; i++) {
            int idx = tid + i * 256;
            int dd = idx >> 6, tt = idx & 63;
            xsl[dd][tt] = lp[(size_t)(d0 + dd) * T + tt];
        }
        __syncthreads();
        int tt = tid & 63, g = tid >> 6;      // g: 16-d subchunk
        c16 v;
#pragma unroll
        for (int j = 0; j < 16; j++) {
            int q = (int)rintf(xsl[g * 16 + j][tt] * inv_sx);
            q = q > 127 ? 127 : (q < -127 ? -127 : q);
            v[j] = (char)q;
        }
        *(c16*)&Ax[(size_t)(m0 + tt) * 512 + d0 + g * 16] = v;
    }
}

// ---- prep B: Be[k][d] = i8 quantized emb (exact scale emax/127) ----------
__global__ __launch_bounds__(256)
void vq_prep_b(const float* __restrict__ emb, signed char* __restrict__ Be) {
    size_t i = ((size_t)blockIdx.x * 256 + threadIdx.x) * 16;
    const float s = 127.0f * 8192.0f;   // 1/se, exact
    c16 v;
#pragma unroll
    for (int j = 0; j < 16; j += 4) {
        float4 e4 = *(const float4*)&emb[i + j];
        int q0 = (int)rintf(e4.x * s), q1 = (int)rintf(e4.y * s);
        int q2 = (int)rintf(e4.z * s), q3 = (int)rintf(e4.w * s);
        q0 = q0 > 127 ? 127 : (q0 < -127 ? -127 : q0);
        q1 = q1 > 127 ? 127 : (q1 < -127 ? -127 : q1);
        q2 = q2 > 127 ? 127 : (q2 < -127 ? -127 : q2);
        q3 = q3 > 127 ? 127 : (q3 < -127 ? -127 : q3);
        v[j] = (char)q0; v[j + 1] = (char)q1; v[j + 2] = (char)q2; v[j + 3] = (char)q3;
    }
    *(c16*)&Be[i] = v;
}

// ---- GEMM: i8 MFMA (K=128/step -> HALF the steps), r13 pipeline ----------
// Byte-identical staging/swizzle/frag addressing (rows stay 128B; chunks
// are 16B). acc in exact i32; d2 = e2 - scl*dot. Dependency-free epilogue.
#define BMg 128
#define BNg 128
#define NCHUNK 2048
#define NSTEPS ((NCHUNK / BNg) * 4)   // 64 steps (K=128 each)

__global__ __launch_bounds__(256, 2)
void vq_gemm(const signed char* __restrict__ Ax,
             const signed char* __restrict__ Be,
             const float* __restrict__ e2g,
             const unsigned int* __restrict__ gmax,
             unsigned int* __restrict__ gmin,
             unsigned char* __restrict__ cnt_seg,
             unsigned short* __restrict__ list) {
    __shared__ signed char As[2][BMg * 128];   // 2 x 16 KB
    __shared__ signed char Bs[2][BNg * 128];   // 2 x 16 KB
    __shared__ float e2s[NCHUNK];              // 8 KB
    __shared__ int cntl[BMg];                  // 512 B

    const int tid = threadIdx.x;
    const int lane = tid & 63;
    const int wid = tid >> 6;
    const int m0 = blockIdx.x * BMg;
    const int nc0 = blockIdx.y * NCHUNK;

    for (int i = tid; i < NCHUNK; i += 256) e2s[i] = e2g[nc0 + i];
    if (tid < BMg) cntl[tid] = 0;
    // scl = 2*sx*se = xmax * 2/(127*127*8192)
    const float scl = ord2f(*gmax) * (2.0f / (127.0f * 127.0f * 8192.0f));
    asm volatile("s_waitcnt lgkmcnt(0)" ::: "memory");

    // staging addresses (pre-swizzled source, linear LDS dest); rows 512B
    const int rbase = wid * 8 + (lane >> 3);
    const int cbyte = (((lane & 7) ^ (lane >> 3)) * 16);
    const char* gA = (const char*)Ax + (size_t)(m0 + rbase) * 512 + cbyte;
    const char* gB = (const char*)Be + (size_t)(nc0 + rbase) * 512 + cbyte;
    const int ldsoff = wid * 1024;

    // fragment read bases (4x1 mapping; row&7 == lane&7; LDS rows 128B)
    const int rbyteA = (wid * 32 + (lane & 15)) * 128;
    const int rbyteB = ((lane & 15)) * 128;

    // prologue: stage step 0 into buffer 0
#pragma unroll
    for (int i = 0; i < 4; i++) {
        gload16(gA + (size_t)i * 16384, (char*)As[0] + ldsoff + i * 4096);
        gload16(gB + (size_t)i * 16384, (char*)Bs[0] + ldsoff + i * 4096);
    }

    float runmin[2][4];
    float thrg[2][4];
#pragma unroll
    for (int mi = 0; mi < 2; mi++)
#pragma unroll
        for (int r = 0; r < 4; r++) runmin[mi][r] = 3.4e38f;

    i32x4 acc[2][8];
    for (int s = 0; s < NSTEPS; s++) {
        const int cur = s & 1;
        const int nt = s >> 2, ks = s & 3;

        // barrier #1: all waves finished reading buf[cur^1] (iter s-1)
        __builtin_amdgcn_s_barrier();

        // issue prefetch(s+1) into buf[cur^1]; wait only for the old batch
        if (s + 1 < NSTEPS) {
            const int nt2 = (s + 1) >> 2, ks2 = (s + 1) & 3;
            const char* ga = gA + (size_t)(ks2 * 128);
            const char* gb = gB + (size_t)(nt2 * 128) * 512 + (size_t)(ks2 * 128);
            char* la = (char*)As[cur ^ 1] + ldsoff;
            char* lb = (char*)Bs[cur ^ 1] + ldsoff;
#pragma unroll
            for (int i = 0; i < 4; i++) {
                gload16(ga + (size_t)i * 16384, la + i * 4096);
                gload16(gb + (size_t)i * 16384, lb + i * 4096);
            }
            asm volatile("s_waitcnt vmcnt(8)" ::: "memory");
        } else {
            asm volatile("s_waitcnt vmcnt(0)" ::: "memory");
        }
        // barrier #2: all waves' buf[cur] stores landed
        __builtin_amdgcn_s_barrier();

        if (ks == 0) {
#pragma unroll
            for (int mi = 0; mi < 2; mi++)
#pragma unroll
                for (int ni = 0; ni < 8; ni++) acc[mi][ni] = (i32x4){0, 0, 0, 0};
            // prefetch gmin thresholds for this tile (consumed at ks==3)
#pragma unroll
            for (int mi = 0; mi < 2; mi++)
#pragma unroll
                for (int r = 0; r < 4; r++) {
                    const int m = m0 + wid * 32 + mi * 16 + (lane >> 4) * 4 + r;
                    thrg[mi][r] = ord2f(gmin[m]);
                }
        }

        __builtin_amdgcn_s_setprio(1);
#pragma unroll
        for (int kh = 0; kh < 2; kh++) {
            const int cb = ((((lane >> 4) + kh * 4) ^ (lane & 7)) * 16);
            i32x4 af[2], bfr[8];
#pragma unroll
            for (int mi = 0; mi < 2; mi++)
                af[mi] = *(const i32x4*)((const char*)As[cur] + rbyteA + mi * 2048 + cb);
#pragma unroll
            for (int ni = 0; ni < 8; ni++)
                bfr[ni] = *(const i32x4*)((const char*)Bs[cur] + rbyteB + ni * 2048 + cb);
#pragma unroll
            for (int mi = 0; mi < 2; mi++)
#pragma unroll
                for (int ni = 0; ni < 8; ni++)
                    acc[mi][ni] = __builtin_amdgcn_mfma_i32_16x16x64_i8(
                        af[mi], bfr[ni], acc[mi][ni], 0, 0, 0);
        }
        __builtin_amdgcn_s_setprio(0);

        if (ks == 3) {
            const int n0l = nt * BNg;
            float d2v[2][8][4];
            // d2 = e2 - scl*dot (exact i32 dot -> exact f32 convert)
#pragma unroll
            for (int mi = 0; mi < 2; mi++)
#pragma unroll
                for (int ni = 0; ni < 8; ni++) {
                    float e2v = e2s[n0l + ni * 16 + (lane & 15)];
#pragma unroll
                    for (int r = 0; r < 4; r++)
                        d2v[mi][ni][r] = e2v - scl * (float)acc[mi][ni][r];
                }
#pragma unroll
            for (int mi = 0; mi < 2; mi++)
#pragma unroll
                for (int r = 0; r < 4; r++) {
                    // wave-local FULL 128-col row min (4x1 mapping)
                    float v = d2v[mi][0][r];
#pragma unroll
                    for (int ni = 1; ni < 8; ni++) v = fminf(v, d2v[mi][ni][r]);
                    v = fminf(v, __shfl_xor(v, 1));
                    v = fminf(v, __shfl_xor(v, 2));
                    v = fminf(v, __shfl_xor(v, 4));
                    v = fminf(v, __shfl_xor(v, 8));
                    runmin[mi][r] = fminf(runmin[mi][r], v);
                    const int rloc = wid * 32 + mi * 16 + (lane >> 4) * 4 + r;
                    const int m = m0 + rloc;
                    float th = fminf(thrg[mi][r], runmin[mi][r]) + WIN;
#pragma unroll
                    for (int ni = 0; ni < 8; ni++) {
                        if (d2v[mi][ni][r] < th) {
                            int kcode = nc0 + n0l + ni * 16 + (lane & 15);
                            int slot = atomicAdd(&cntl[rloc], 1);   // LDS atomic
                            if (slot < CAP_SEG)
                                list[m * 192 + blockIdx.y * CAP_SEG + slot] =
                                    (unsigned short)kcode;
                        }
                    }
                    // share min: fire-and-forget (return unused)
                    if ((lane & 15) == 0)
                        atomicMin(&gmin[m], f2ord(runmin[mi][r]));
                }
        }
    }

    // store segment counts (u8, clamped)
    __syncthreads();
    if (tid < BMg) {
        int c = cntl[tid];
        cnt_seg[(size_t)(m0 + tid) * 4 + blockIdx.y] =
            (unsigned char)(c > 255 ? 255 : c);
    }
}

// ---- rescore + FUSED gather; 2-way candidate interleave (VALIDATED r18) --
__global__ __launch_bounds__(256)
void vq_rescore3(const float* __restrict__ lat, const float* __restrict__ emb,
                 const float* __restrict__ x2g, const float* __restrict__ e2g,
                 const unsigned char* __restrict__ cnt_seg,
                 const unsigned short* __restrict__ list,
                 int* __restrict__ ids, int* __restrict__ ovfc,
                 int* __restrict__ ovfl, unsigned long long* __restrict__ best,
                 float* __restrict__ out) {
#pragma clang fp contract(off)
    __shared__ float xs[D][32];                    // 64 KB (reused for gather)
    __shared__ unsigned long long bests[8][32];    // 2 KB
    __shared__ int kid_s[32];

    const int tid = threadIdx.x;
    const int w = tid >> 5;        // candidate-slot group (8)
    const int l = tid & 31;        // point within block (32)
    const int m0 = blockIdx.x * 32;
    const int b = m0 / T, t0 = m0 % T;
    const int p = m0 + l;
    const size_t lbase = (size_t)b * D * T + t0;

#pragma unroll
    for (int i = 0; i < 64; i++) {
        int idx = tid + i * 256;
        int dd = idx >> 5, tt = idx & 31;
        xs[dd][tt] = lat[lbase + (size_t)dd * T + tt];
    }

    unsigned int cs = *(const unsigned int*)&cnt_seg[(size_t)p * 4];
    int c0 = cs & 255, c1 = (cs >> 8) & 255, c2 = (cs >> 16) & 255, c3 = (cs >> 24) & 255;
    const bool ovf = (c0 > CAP_SEG) | (c1 > CAP_SEG) | (c2 > CAP_SEG) | (c3 > CAP_SEG);
    if (w == 0 && ovf) {
        int s = atomicAdd(ovfc, 1);
        ovfl[s] = p;
        best[p] = ~0ull;
    }
    __syncthreads();

    const float x2v = x2g[p];
    unsigned long long bb = ~0ull;
    if (!ovf) {
        int segc[4] = {c0, c1, c2, c3};
#pragma unroll
        for (int seg = 0; seg < 4; seg++) {
            const int c = segc[seg];
            int j = w;
            for (; j + 8 < c; j += 16) {   // two independent exact chains
                int ka = list[(size_t)p * 192 + seg * CAP_SEG + j];
                int kb = list[(size_t)p * 192 + seg * CAP_SEG + j + 8];
                const float4* ea4 = (const float4*)(emb + (size_t)ka * D);
                const float4* eb4 = (const float4*)(emb + (size_t)kb * D);
                float aA = 0.f, aB = 0.f;
#pragma unroll 4
                for (int q = 0; q < D / 4; q++) {
                    float4 va = ea4[q];
                    float4 vb = eb4[q];
                    float x0 = xs[q * 4 + 0][l], x1 = xs[q * 4 + 1][l];
                    float x2_ = xs[q * 4 + 2][l], x3 = xs[q * 4 + 3][l];
                    aA = __fadd_rn(aA, __fmul_rn(x0, va.x));
                    aB = __fadd_rn(aB, __fmul_rn(x0, vb.x));
                    aA = __fadd_rn(aA, __fmul_rn(x1, va.y));
                    aB = __fadd_rn(aB, __fmul_rn(x1, vb.y));
                    aA = __fadd_rn(aA, __fmul_rn(x2_, va.z));
                    aB = __fadd_rn(aB, __fmul_rn(x2_, vb.z));
                    aA = __fadd_rn(aA, __fmul_rn(x3, va.w));
                    aB = __fadd_rn(aB, __fmul_rn(x3, vb.w));
                }
                float dA = __fadd_rn(__fsub_rn(x2v, __fadd_rn(aA, aA)), e2g[ka]);
                float dB = __fadd_rn(__fsub_rn(x2v, __fadd_rn(aB, aB)), e2g[kb]);
                unsigned long long pa = ((unsigned long long)f2ord(dA) << 32) |
                                        (unsigned long long)(unsigned int)ka;
                unsigned long long pb = ((unsigned long long)f2ord(dB) << 32) |
                                        (unsigned long long)(unsigned int)kb;
                bb = (pa < bb) ? pa : bb;
                bb = (pb < bb) ? pb : bb;
            }
            if (j < c) {
                int k = list[(size_t)p * 192 + seg * CAP_SEG + j];
                const float4* er4 = (const float4*)(emb + (size_t)k * D);
                float acc = 0.f;
#pragma unroll 4
                for (int q = 0; q < D / 4; q++) {
                    float4 e4 = er4[q];
                    acc = __fadd_rn(acc, __fmul_rn(xs[q * 4 + 0][l], e4.x));
                    acc = __fadd_rn(acc, __fmul_rn(xs[q * 4 + 1][l], e4.y));
                    acc = __fadd_rn(acc, __fmul_rn(xs[q * 4 + 2][l], e4.z));
                    acc = __fadd_rn(acc, __fmul_rn(xs[q * 4 + 3][l], e4.w));
                }
                float dist = __fadd_rn(__fsub_rn(x2v, __fadd_rn(acc, acc)), e2g[k]);
                unsigned long long pk = ((unsigned long long)f2ord(dist) << 32) |
                                        (unsigned long long)(unsigned int)k;
                bb = (pk < bb) ? pk : bb;
            }
        }
    }
    bests[w][l] = bb;
    __syncthreads();

    if (tid < 32) {
        unsigned int cs2 = *(const unsigned int*)&cnt_seg[(size_t)(m0 + tid) * 4];
        bool ov2 = ((cs2 & 255) > CAP_SEG) | (((cs2 >> 8) & 255) > CAP_SEG) |
                   (((cs2 >> 16) & 255) > CAP_SEG) | (((cs2 >> 24) & 255) > CAP_SEG);
        if (!ov2) {
            unsigned long long v = bests[0][tid];
#pragma unroll
            for (int i = 1; i < 8; i++) v = (bests[i][tid] < v) ? bests[i][tid] : v;
            int kk = (int)(v & 0xFFFFFFFFull);
            ids[m0 + tid] = kk;
            kid_s[tid] = kk;
        } else {
            kid_s[tid] = -1;
        }
    }
    __syncthreads();

    // fused gather: ebuf aliases xs storage (32 rows x 65 floats)
    float* ebuf = &xs[0][0];
    float* outb = out + (size_t)b * D * T + t0;
    for (int d0 = 0; d0 < D; d0 += 64) {
        if (d0) __syncthreads();
#pragma unroll
        for (int i = 0; i < 8; i++) {
            int idx = tid + i * 256;
            int tt = idx >> 6, dd = idx & 63;
            int kk = kid_s[tt];
            ebuf[tt * 65 + dd] = emb[(size_t)(kk < 0 ? 0 : kk) * D + d0 + dd];
        }
        __syncthreads();
#pragma unroll
        for (int i = 0; i < 8; i++) {
            int idx = tid + i * 256;
            int tt = idx & 31, dd = idx >> 5;
            if (kid_s[tt] >= 0)
                outb[(size_t)(d0 + dd) * T + tt] = ebuf[tt * 65 + dd];
        }
    }
}

// ---- PARALLEL exact scan for overflow points (8 k-slices x blocks) -------
__global__ __launch_bounds__(256)
void vq_fallback_par(const float* __restrict__ lat, const float* __restrict__ emb,
                     const float* __restrict__ x2g, const float* __restrict__ e2g,
                     const int* __restrict__ ovfc, const int* __restrict__ ovfl,
                     unsigned long long* __restrict__ best) {
#pragma clang fp contract(off)
    __shared__ float xr[D];
    __shared__ unsigned long long wmin[4];
    const int n = *ovfc;
    const int ntask = n * 8;
    for (int task = blockIdx.x; task < ntask; task += gridDim.x) {
        const int m = ovfl[task >> 3];
        const int slice = task & 7;
        const int b = m / T, t = m % T;
        for (int d = threadIdx.x; d < D; d += 256)
            xr[d] = lat[(size_t)b * D * T + (size_t)d * T + t];
        __syncthreads();
        const float x2v = x2g[m];
        unsigned long long bl = ~0ull;
        for (int k = slice * 1024 + threadIdx.x; k < slice * 1024 + 1024; k += 256) {
            const float* er = emb + (size_t)k * D;
            float s = 0.f;
            for (int d = 0; d < D; d++)
                s = __fadd_rn(s, __fmul_rn(xr[d], er[d]));
            float tmp = __fsub_rn(x2v, __fadd_rn(s, s));
            float dist = __fadd_rn(tmp, e2g[k]);
            unsigned long long pk = ((unsigned long long)f2ord(dist) << 32) |
                                    (unsigned long long)(unsigned int)k;
            bl = (pk < bl) ? pk : bl;
        }
#pragma unroll
        for (int off = 1; off < 64; off <<= 1) {
            unsigned long long o = __shfl_xor(bl, off);
            bl = (o < bl) ? o : bl;
        }
        if ((threadIdx.x & 63) == 0) wmin[threadIdx.x >> 6] = bl;
        __syncthreads();
        if (threadIdx.x == 0) {
            unsigned long long v = wmin[0];
            for (int i = 1; i < 4; i++) v = (wmin[i] < v) ? wmin[i] : v;
            atomicMin(&best[m], v);
        }
        __syncthreads();
    }
}

// ---- finalize overflow ids from packed best ------------------------------
__global__ __launch_bounds__(256)
void vq_finalize(const int* __restrict__ ovfc, const int* __restrict__ ovfl,
                 const unsigned long long* __restrict__ best, int* __restrict__ ids) {
    const int n = *ovfc;
    for (int i = blockIdx.x * 256 + threadIdx.x; i < n; i += gridDim.x * 256) {
        int m = ovfl[i];
        ids[m] = (int)(best[m] & 0xFFFFFFFFull);
    }
}

// ---- gather for overflow points only (rare; one block per point) ---------
__global__ __launch_bounds__(256)
void vq_gather_ovf(const float* __restrict__ emb, const int* __restrict__ ovfc,
                   const int* __restrict__ ovfl, const int* __restrict__ ids,
                   float* __restrict__ out) {
    const int n = *ovfc;
    for (int i = blockIdx.x; i < n; i += gridDim.x) {
        int m = ovfl[i];
        int b = m / T, t = m % T;
        int k = ids[m];
        for (int d = threadIdx.x; d < D; d += 256)
            out[(size_t)b * D * T + (size_t)d * T + t] = emb[(size_t)k * D + d];
    }
}

// ================= round-3 validated fallback path (small ws) =============
#define TM 64
#define TN 128
#define TD 32
__global__ __launch_bounds__(256)
void vq_main_old(const float* __restrict__ latents, const float* __restrict__ emb,
                 const float* __restrict__ x2g, const float* __restrict__ e2g,
                 float* __restrict__ out) {
#pragma clang fp contract(off)
    __shared__ __align__(16) float xs[TD][TM];
    __shared__ __align__(16) float es[TD][TN + 4];
    __shared__ float e2s[TN];
    __shared__ float x2s[TM];
    __shared__ int ids_s[TM];
    __shared__ __align__(16) float gbuf[64][65];
    const int tid = threadIdx.x;
    const int tn = tid & 15;
    const int tm = tid >> 4;
    const int m0 = blockIdx.x * TM;
    const int b = m0 / T;
    const int t0 = m0 % T;
    const float* lat = latents + (size_t)b * D * T + t0;
    if (tid < TM) x2s[tid] = x2g[m0 + tid];
    float minv[4];
    int mini[4];
#pragma unroll
    for (int i = 0; i < 4; i++) { minv[i] = 3.4e38f; mini[i] = 0; }
    for (int k0 = 0; k0 < K; k0 += TN) {
        __syncthreads();
        if (tid < TN) e2s[tid] = e2g[k0 + tid];
        float s[4][8];
#pragma unroll
        for (int i = 0; i < 4; i++)
#pragma unroll
            for (int j = 0; j < 8; j++) s[i][j] = 0.0f;
        for (int d0 = 0; d0 < D; d0 += TD) {
            if (d0) __syncthreads();
#pragma unroll
            for (int i = 0; i < 8; i++) {
                int idx = tid + i * 256;
                int dd = idx >> 6, tt = idx & 63;
                xs[dd][tt] = lat[(size_t)(d0 + dd) * T + tt];
            }
#pragma unroll
            for (int i = 0; i < 16; i++) {
                int idx = tid + i * 256;
                int nn = idx >> 5, dd = idx & 31;
                es[dd][nn] = emb[(size_t)(k0 + nn) * D + d0 + dd];
            }
            __syncthreads();
#pragma unroll
            for (int d = 0; d < TD; d++) {
                float4 xr = *(const float4*)&xs[d][tm * 4];
                float4 ea = *(const float4*)&es[d][tn * 4];
                float4 eb = *(const float4*)&es[d][64 + tn * 4];
                float xv[4] = {xr.x, xr.y, xr.z, xr.w};
                float ev[8] = {ea.x, ea.y, ea.z, ea.w, eb.x, eb.y, eb.z, eb.w};
#pragma unroll
                for (int i = 0; i < 4; i++)
#pragma unroll
                    for (int j = 0; j < 8; j++)
                        s[i][j] = __fadd_rn(s[i][j], __fmul_rn(xv[i], ev[j]));
            }
        }
#pragma unroll
        for (int i = 0; i < 4; i++) {
            float x2v = x2s[tm * 4 + i];
#pragma unroll
            for (int j = 0; j < 8; j++) {
                int col = (j < 4) ? (tn * 4 + j) : (64 + tn * 4 + (j - 4));
                float s2 = __fadd_rn(s[i][j], s[i][j]);
                float tmp = __fsub_rn(x2v, s2);
                float dist = __fadd_rn(tmp, e2s[col]);
                int kk = k0 + col;
                if (dist < minv[i]) { minv[i] = dist; mini[i] = kk; }
            }
        }
    }
#pragma unroll
    for (int i = 0; i < 4; i++) {
        float v1 = minv[i];
        int i1 = mini[i];
#pragma unroll
        for (int off = 1; off < 16; off <<= 1) {
            float ov = __shfl_xor(v1, off);
            int oi = __shfl_xor(i1, off);
            if (ov < v1 || (ov == v1 && oi < i1)) { v1 = ov; i1 = oi; }
        }
        if (tn == 0) ids_s[tm * 4 + i] = i1;
    }
    __syncthreads();
    float* outb = out + (size_t)b * D * T + t0;
    for (int d0 = 0; d0 < D; d0 += 64) {
        if (d0) __syncthreads();
#pragma unroll
        for (int i = 0; i < 16; i++) {
            int idx = tid + i * 256;
            int tt = idx >> 6, dd = idx & 63;
            gbuf[tt][dd] = emb[(size_t)ids_s[tt] * D + d0 + dd];
        }
        __syncthreads();
#pragma unroll
        for (int i = 0; i < 16; i++) {
            int idx = tid + i * 256;
            int dd = idx >> 6, tt = idx & 63;
            outb[(size_t)(d0 + dd) * T + tt] = gbuf[tt][dd];
        }
    }
}

extern "C" void kernel_launch(void* const* d_in, const int* in_sizes, int n_in,
                              void* d_out, int out_size, void* d_ws, size_t ws_size,
                              hipStream_t stream) {
    const float* latents = (const float*)d_in[0];
    const float* emb     = (const float*)d_in[1];
    float* out = (float*)d_out;
    char* ws = (char*)d_ws;
    float* x2g = (float*)(ws + WS_X2);
    float* e2g = (float*)(ws + WS_E2);

    if (ws_size < (size_t)WS_NEED) {   // validated round-3 path
        hipLaunchKernelGGL(vq_x2_kernel, dim3(M / 256), dim3(256), 0, stream, latents, x2g);
        hipLaunchKernelGGL(vq_e2_kernel, dim3(K / 256), dim3(256), 0, stream, emb, e2g);
        hipLaunchKernelGGL(vq_main_old, dim3(M / TM), dim3(256), 0, stream,
                           latents, emb, x2g, e2g, out);
        return;
    }

    unsigned char* cnt_seg = (unsigned char*)(ws + WS_CNT);
    int* ids = (int*)(ws + WS_IDS);
    int* ovfc = (int*)(ws + WS_OVFC);
    unsigned int* gmax = (unsigned int*)(ws + WS_XMAX);
    int* ovfl = (int*)(ws + WS_OVFL);
    unsigned long long* best = (unsigned long long*)(ws + WS_BEST);
    unsigned int* gmin = (unsigned int*)(ws + WS_GMIN);
    unsigned short* list = (unsigned short*)(ws + WS_LIST);
    signed char* Ax = (signed char*)(ws + WS_AX);
    signed char* Be = (signed char*)(ws + WS_BE);

    hipLaunchKernelGGL(vq_x2_init, dim3(M / 256), dim3(256), 0, stream,
                       latents, x2g, (unsigned int*)cnt_seg, ovfc, gmin, gmax);
    hipLaunchKernelGGL(vq_e2_kernel, dim3(K / 256), dim3(256), 0, stream, emb, e2g);
    hipLaunchKernelGGL(vq_prep_a, dim3(M / 64), dim3(256), 0, stream, latents, Ax, gmax);
    hipLaunchKernelGGL(vq_prep_b, dim3((K * D) / 4096), dim3(256), 0, stream, emb, Be);
    hipLaunchKernelGGL(vq_gemm, dim3(M / BMg, K / NCHUNK), dim3(256), 0, stream,
                       Ax, Be, e2g, gmax, gmin, cnt_seg, list);
    hipLaunchKernelGGL(vq_rescore3, dim3(M / 32), dim3(256), 0, stream,
                       latents, emb, x2g, e2g, cnt_seg, list, ids, ovfc, ovfl, best, out);
    hipLaunchKernelGGL(vq_fallback_par, dim3(512), dim3(256), 0, stream,
                       latents, emb, x2g, e2g, ovfc, ovfl, best);
    hipLaunchKernelGGL(vq_finalize, dim3(64), dim3(256), 0, stream,
                       ovfc, ovfl, best, ids);
    hipLaunchKernelGGL(vq_gather_ovf, dim3(128), dim3(256), 0, stream,
                       emb, ovfc, ovfl, ids, out);
}

// Round 20
// 412.438 us; speedup vs baseline: 71.0943x; 71.0943x over previous
//
#include <hip/hip_runtime.h>

#define B 8
#define D 512
#define T 2048
#define K 8192
#define M (B*T)

typedef float f32x4 __attribute__((ext_vector_type(4)));
typedef short bf16x8 __attribute__((ext_vector_type(8)));
typedef unsigned short us8 __attribute__((ext_vector_type(8)));

#define CAP_SEG 48          // per-y-segment candidate cap (4 segs x 48 = 192)
#define WIN 1.6e-3f         // bf16 path: 2*delta <= 1.3e-3 (r4/r5-validated)

// ws layout (bytes)
#define WS_X2    0                  // f32[M]      65536
#define WS_E2    65536              // f32[K]      32768
#define WS_CNT   98304              // u8[M*4]     65536 (segment counts)
#define WS_IDS   163840             // i32[M]      65536
#define WS_OVFC  229376             // i32         256
#define WS_OVFL  229632             // i32[M]      65536
#define WS_BEST  295168             // u64[M]      131072
#define WS_GMIN  426240             // u32[M]      65536
#define WS_LIST  491776             // u16[M*192]  6291456
#define WS_AX    6783232            // bf16[M*512] 16777216
#define WS_BE    23560448           // bf16[K*512] 8388608
#define WS_NEED  31949056

__device__ inline unsigned short f2bf(float f) {   // RNE f32->bf16
    unsigned int x = __float_as_uint(f);
    unsigned int r = x + 0x7fffu + ((x >> 16) & 1u);
    return (unsigned short)(r >> 16);
}

// order-preserving f32 <-> u32 (no NaNs in data)
__device__ inline unsigned int f2ord(float f) {
    unsigned int u = __float_as_uint(f);
    return (u & 0x80000000u) ? ~u : (u | 0x80000000u);
}
__device__ inline float ord2f(unsigned int u) {
    return __uint_as_float((u & 0x80000000u) ? (u & 0x7fffffffu) : ~u);
}

__device__ inline void gload16(const void* g, void* l) {
    __builtin_amdgcn_global_load_lds(
        (const __attribute__((address_space(1))) unsigned int*)g,
        (__attribute__((address_space(3))) unsigned int*)l, 16, 0, 0);
}

// ---- x2 + init fused: numpy-pairwise x2 (VALIDATED r3) + zero cnt/gmin ---
__global__ __launch_bounds__(256)
void vq_x2_init(const float* __restrict__ lat, float* __restrict__ x2g,
                unsigned int* __restrict__ cnt_seg_u32, int* __restrict__ ovfc,
                unsigned int* __restrict__ gmin) {
#pragma clang fp contract(off)
    int p = blockIdx.x * 256 + threadIdx.x;
    cnt_seg_u32[p] = 0;
    gmin[p] = 0xFFFFFFFFu;
    if (p == 0) *ovfc = 0;
    int b = p / T, t = p % T;
    const float* base = lat + (size_t)b * D * T + t;
    float blk[4];
#pragma unroll
    for (int q = 0; q < 4; q++) {
        float r[8];
#pragma unroll
        for (int j = 0; j < 8; j++) {
            float v = base[(size_t)(q * 128 + j) * T];
            r[j] = __fmul_rn(v, v);
        }
        for (int i = 8; i < 128; i += 8) {
#pragma unroll
            for (int j = 0; j < 8; j++) {
                float v = base[(size_t)(q * 128 + i + j) * T];
                r[j] = __fadd_rn(r[j], __fmul_rn(v, v));
            }
        }
        blk[q] = __fadd_rn(__fadd_rn(__fadd_rn(r[0], r[1]), __fadd_rn(r[2], r[3])),
                           __fadd_rn(__fadd_rn(r[4], r[5]), __fadd_rn(r[6], r[7])));
    }
    x2g[p] = __fadd_rn(__fadd_rn(blk[0], blk[1]), __fadd_rn(blk[2], blk[3]));
}

// ---- x2 plain (small-ws fallback path) -----------------------------------
__global__ __launch_bounds__(256)
void vq_x2_kernel(const float* __restrict__ lat, float* __restrict__ x2g) {
#pragma clang fp contract(off)
    int p = blockIdx.x * 256 + threadIdx.x;
    int b = p / T, t = p % T;
    const float* base = lat + (size_t)b * D * T + t;
    float blk[4];
#pragma unroll
    for (int q = 0; q < 4; q++) {
        float r[8];
#pragma unroll
        for (int j = 0; j < 8; j++) {
            float v = base[(size_t)(q * 128 + j) * T];
            r[j] = __fmul_rn(v, v);
        }
        for (int i = 8; i < 128; i += 8) {
#pragma unroll
            for (int j = 0; j < 8; j++) {
                float v = base[(size_t)(q * 128 + i + j) * T];
                r[j] = __fadd_rn(r[j], __fmul_rn(v, v));
            }
        }
        blk[q] = __fadd_rn(__fadd_rn(__fadd_rn(r[0], r[1]), __fadd_rn(r[2], r[3])),
                           __fadd_rn(__fadd_rn(r[4], r[5]), __fadd_rn(r[6], r[7])));
    }
    x2g[p] = __fadd_rn(__fadd_rn(blk[0], blk[1]), __fadd_rn(blk[2], blk[3]));
}

// ---- e2[k]: numpy-pairwise tree, float4 loads (VALIDATED r13) ------------
__global__ __launch_bounds__(256)
void vq_e2_kernel(const float* __restrict__ emb, float* __restrict__ e2g) {
#pragma clang fp contract(off)
    int k = blockIdx.x * 256 + threadIdx.x;
    const float* base = emb + (size_t)k * D;
    float blk[4];
#pragma unroll
    for (int q = 0; q < 4; q++) {
        float r[8];
        {
            float4 a = *(const float4*)&base[q * 128];
            float4 c = *(const float4*)&base[q * 128 + 4];
            r[0] = __fmul_rn(a.x, a.x); r[1] = __fmul_rn(a.y, a.y);
            r[2] = __fmul_rn(a.z, a.z); r[3] = __fmul_rn(a.w, a.w);
            r[4] = __fmul_rn(c.x, c.x); r[5] = __fmul_rn(c.y, c.y);
            r[6] = __fmul_rn(c.z, c.z); r[7] = __fmul_rn(c.w, c.w);
        }
        for (int i = 8; i < 128; i += 8) {
            float4 a = *(const float4*)&base[q * 128 + i];
            float4 c = *(const float4*)&base[q * 128 + i + 4];
            r[0] = __fadd_rn(r[0], __fmul_rn(a.x, a.x));
            r[1] = __fadd_rn(r[1], __fmul_rn(a.y, a.y));
            r[2] = __fadd_rn(r[2], __fmul_rn(a.z, a.z));
            r[3] = __fadd_rn(r[3], __fmul_rn(a.w, a.w));
            r[4] = __fadd_rn(r[4], __fmul_rn(c.x, c.x));
            r[5] = __fadd_rn(r[5], __fmul_rn(c.y, c.y));
            r[6] = __fadd_rn(r[6], __fmul_rn(c.z, c.z));
            r[7] = __fadd_rn(r[7], __fmul_rn(c.w, c.w));
        }
        blk[q] = __fadd_rn(__fadd_rn(__fadd_rn(r[0], r[1]), __fadd_rn(r[2], r[3])),
                           __fadd_rn(__fadd_rn(r[4], r[5]), __fadd_rn(r[6], r[7])));
    }
    e2g[k] = __fadd_rn(__fadd_rn(blk[0], blk[1]), __fadd_rn(blk[2], blk[3]));
}

// ---- prep A: Ax[m][d] = bf16(latents[b][d][t]) (VALIDATED round 4) -------
__global__ __launch_bounds__(256)
void vq_prep_a(const float* __restrict__ lat, unsigned short* __restrict__ Ax) {
    __shared__ float xsl[64][65];
    const int tid = threadIdx.x;
    const int m0 = blockIdx.x * 64;
    const int b = m0 / T, t0 = m0 % T;
    const float* lp = lat + (size_t)b * D * T + t0;
    for (int d0 = 0; d0 < D; d0 += 64) {
        if (d0) __syncthreads();
#pragma unroll
        for (int i = 0; i < 16; i++) {
            int idx = tid + i * 256;
            int dd = idx >> 6, tt = idx & 63;
            xsl[dd][tt] = lp[(size_t)(d0 + dd) * T + tt];
        }
        __syncthreads();
        int tt = tid & 63, g = tid >> 6;
        us8 va, vb;
#pragma unroll
        for (int j = 0; j < 8; j++) va[j] = f2bf(xsl[g * 16 + j][tt]);
#pragma unroll
        for (int j = 0; j < 8; j++) vb[j] = f2bf(xsl[g * 16 + 8 + j][tt]);
        *(us8*)&Ax[(size_t)(m0 + tt) * 512 + d0 + g * 16] = va;
        *(us8*)&Ax[(size_t)(m0 + tt) * 512 + d0 + g * 16 + 8] = vb;
    }
}

// ---- prep B: Be[k][d] = bf16(emb[k][d]) (VALIDATED round 4) --------------
__global__ __launch_bounds__(256)
void vq_prep_b(const float* __restrict__ emb, unsigned short* __restrict__ Be) {
    size_t i = ((size_t)blockIdx.x * 256 + threadIdx.x) * 4;
    float4 v = *(const float4*)&emb[i];
    ushort4 o;
    o.x = f2bf(v.x); o.y = f2bf(v.y); o.z = f2bf(v.z); o.w = f2bf(v.w);
    *(ushort4*)&Be[i] = o;
}

// ---- GEMM: single-buffered m97-structure, 3 blocks/CU (VALIDATED r18) ----
#define BMg 128
#define BNg 128
#define NCHUNK 2048
#define NSTEPS ((NCHUNK / BNg) * 8)

__global__ __launch_bounds__(256, 3)
void vq_gemm(const unsigned short* __restrict__ Ax,
             const unsigned short* __restrict__ Be,
             const float* __restrict__ e2g,
             unsigned int* __restrict__ gmin,
             unsigned char* __restrict__ cnt_seg,
             unsigned short* __restrict__ list) {
    __shared__ unsigned short As[BMg * 64];      // 16 KB
    __shared__ unsigned short Bs[BNg * 64];      // 16 KB
    __shared__ float e2s[NCHUNK];                // 8 KB
    __shared__ int cntl[BMg];                    // 512 B

    const int tid = threadIdx.x;
    const int lane = tid & 63;
    const int wid = tid >> 6;
    const int m0 = blockIdx.x * BMg;
    const int nc0 = blockIdx.y * NCHUNK;

    for (int i = tid; i < NCHUNK; i += 256) e2s[i] = e2g[nc0 + i];
    if (tid < BMg) cntl[tid] = 0;

    // staging addresses (pre-swizzled source, linear LDS dest)
    const int rbase = wid * 8 + (lane >> 3);
    const int cbyte = (((lane & 7) ^ (lane >> 3)) * 16);
    const char* gA = (const char*)Ax + (size_t)(m0 + rbase) * 1024 + cbyte;
    const char* gB = (const char*)Be + (size_t)(nc0 + rbase) * 1024 + cbyte;
    const int ldsoff = wid * 1024;

    // fragment read bases (4x1 mapping; row&7 == lane&7)
    const int rbyteA = (wid * 32 + (lane & 15)) * 128;
    const int rbyteB = ((lane & 15)) * 128;

    float runmin[2][4];
    float thrg[2][4];
#pragma unroll
    for (int mi = 0; mi < 2; mi++)
#pragma unroll
        for (int r = 0; r < 4; r++) runmin[mi][r] = 3.4e38f;

    f32x4 acc[2][8];
    for (int s = 0; s < NSTEPS; s++) {
        const int nt = s >> 3, ks = s & 7;

        // all waves finished reading the buffer from the previous step
        __syncthreads();

        // stage step s into the (single) buffer
        {
            const char* ga = gA + (size_t)(ks * 128);
            const char* gb = gB + (size_t)(nt * 128) * 1024 + (size_t)(ks * 128);
#pragma unroll
            for (int i = 0; i < 4; i++) {
                gload16(ga + (size_t)i * 32768, (char*)As + ldsoff + i * 4096);
                gload16(gb + (size_t)i * 32768, (char*)Bs + ldsoff + i * 4096);
            }
        }
        __syncthreads();   // drains vmcnt -> buffer valid for all waves

        if (ks == 0) {
#pragma unroll
            for (int mi = 0; mi < 2; mi++)
#pragma unroll
                for (int ni = 0; ni < 8; ni++) acc[mi][ni] = (f32x4){0.f, 0.f, 0.f, 0.f};
            // prefetch gmin thresholds for this tile (consumed at ks==7)
#pragma unroll
            for (int mi = 0; mi < 2; mi++)
#pragma unroll
                for (int r = 0; r < 4; r++) {
                    const int m = m0 + wid * 32 + mi * 16 + (lane >> 4) * 4 + r;
                    thrg[mi][r] = ord2f(gmin[m]);
                }
        }

        __builtin_amdgcn_s_setprio(1);
#pragma unroll
        for (int kh = 0; kh < 2; kh++) {
            const int cb = ((((lane >> 4) + kh * 4) ^ (lane & 7)) * 16);
            bf16x8 af[2], bfr[8];
#pragma unroll
            for (int mi = 0; mi < 2; mi++)
                af[mi] = *(const bf16x8*)((const char*)As + rbyteA + mi * 2048 + cb);
#pragma unroll
            for (int ni = 0; ni < 8; ni++)
                bfr[ni] = *(const bf16x8*)((const char*)Bs + rbyteB + ni * 2048 + cb);
#pragma unroll
            for (int mi = 0; mi < 2; mi++)
#pragma unroll
                for (int ni = 0; ni < 8; ni++)
                    acc[mi][ni] = __builtin_amdgcn_mfma_f32_16x16x32_bf16(
                        af[mi], bfr[ni], acc[mi][ni], 0, 0, 0);
        }
        __builtin_amdgcn_s_setprio(0);

        if (ks == 7) {
            const int n0l = nt * BNg;
            // d2 = e2 - 2*dot
#pragma unroll
            for (int mi = 0; mi < 2; mi++)
#pragma unroll
                for (int ni = 0; ni < 8; ni++) {
                    float e2v = e2s[n0l + ni * 16 + (lane & 15)];
#pragma unroll
                    for (int r = 0; r < 4; r++)
                        acc[mi][ni][r] = e2v - 2.0f * acc[mi][ni][r];
                }
#pragma unroll
            for (int mi = 0; mi < 2; mi++)
#pragma unroll
                for (int r = 0; r < 4; r++) {
                    // wave-local FULL 128-col row min (4x1 mapping)
                    float v = acc[mi][0][r];
#pragma unroll
                    for (int ni = 1; ni < 8; ni++) v = fminf(v, acc[mi][ni][r]);
                    v = fminf(v, __shfl_xor(v, 1));
                    v = fminf(v, __shfl_xor(v, 2));
                    v = fminf(v, __shfl_xor(v, 4));
                    v = fminf(v, __shfl_xor(v, 8));
                    runmin[mi][r] = fminf(runmin[mi][r], v);
                    const int rloc = wid * 32 + mi * 16 + (lane >> 4) * 4 + r;
                    const int m = m0 + rloc;
                    float th = fminf(thrg[mi][r], runmin[mi][r]) + WIN;
#pragma unroll
                    for (int ni = 0; ni < 8; ni++) {
                        if (acc[mi][ni][r] < th) {
                            int kcode = nc0 + n0l + ni * 16 + (lane & 15);
                            int slot = atomicAdd(&cntl[rloc], 1);   // LDS atomic
                            if (slot < CAP_SEG)
                                list[m * 192 + blockIdx.y * CAP_SEG + slot] =
                                    (unsigned short)kcode;
                        }
                    }
                    // share min: fire-and-forget (return unused)
                    if ((lane & 15) == 0)
                        atomicMin(&gmin[m], f2ord(runmin[mi][r]));
                }
        }
    }

    // store segment counts (u8, clamped)
    __syncthreads();
    if (tid < BMg) {
        int c = cntl[tid];
        cnt_seg[(size_t)(m0 + tid) * 4 + blockIdx.y] =
            (unsigned char)(c > 255 ? 255 : c);
    }
}

// ---- rescore + FUSED gather; 2-way candidate interleave (VALIDATED r18) --
__global__ __launch_bounds__(256)
void vq_rescore3(const float* __restrict__ lat, const float* __restrict__ emb,
                 const float* __restrict__ x2g, const float* __restrict__ e2g,
                 const unsigned char* __restrict__ cnt_seg,
                 const unsigned short* __restrict__ list,
                 int* __restrict__ ids, int* __restrict__ ovfc,
                 int* __restrict__ ovfl, unsigned long long* __restrict__ best,
                 float* __restrict__ out) {
#pragma clang fp contract(off)
    __shared__ float xs[D][32];                    // 64 KB (reused for gather)
    __shared__ unsigned long long bests[8][32];    // 2 KB
    __shared__ int kid_s[32];

    const int tid = threadIdx.x;
    const int w = tid >> 5;        // candidate-slot group (8)
    const int l = tid & 31;        // point within block (32)
    const int m0 = blockIdx.x * 32;
    const int b = m0 / T, t0 = m0 % T;
    const int p = m0 + l;
    const size_t lbase = (size_t)b * D * T + t0;

#pragma unroll
    for (int i = 0; i < 64; i++) {
        int idx = tid + i * 256;
        int dd = idx >> 5, tt = idx & 31;
        xs[dd][tt] = lat[lbase + (size_t)dd * T + tt];
    }

    unsigned int cs = *(const unsigned int*)&cnt_seg[(size_t)p * 4];
    int c0 = cs & 255, c1 = (cs >> 8) & 255, c2 = (cs >> 16) & 255, c3 = (cs >> 24) & 255;
    const bool ovf = (c0 > CAP_SEG) | (c1 > CAP_SEG) | (c2 > CAP_SEG) | (c3 > CAP_SEG);
    if (w == 0 && ovf) {
        int s = atomicAdd(ovfc, 1);
        ovfl[s] = p;
        best[p] = ~0ull;
    }
    __syncthreads();

    const float x2v = x2g[p];
    unsigned long long bb = ~0ull;
    if (!ovf) {
        int segc[4] = {c0, c1, c2, c3};
#pragma unroll
        for (int seg = 0; seg < 4; seg++) {
            const int c = segc[seg];
            int j = w;
            for (; j + 8 < c; j += 16) {   // two independent exact chains
                int ka = list[(size_t)p * 192 + seg * CAP_SEG + j];
                int kb = list[(size_t)p * 192 + seg * CAP_SEG + j + 8];
                const float4* ea4 = (const float4*)(emb + (size_t)ka * D);
                const float4* eb4 = (const float4*)(emb + (size_t)kb * D);
                float aA = 0.f, aB = 0.f;
#pragma unroll 4
                for (int q = 0; q < D / 4; q++) {
                    float4 va = ea4[q];
                    float4 vb = eb4[q];
                    float x0 = xs[q * 4 + 0][l], x1 = xs[q * 4 + 1][l];
                    float x2_ = xs[q * 4 + 2][l], x3 = xs[q * 4 + 3][l];
                    aA = __fadd_rn(aA, __fmul_rn(x0, va.x));
                    aB = __fadd_rn(aB, __fmul_rn(x0, vb.x));
                    aA = __fadd_rn(aA, __fmul_rn(x1, va.y));
                    aB = __fadd_rn(aB, __fmul_rn(x1, vb.y));
                    aA = __fadd_rn(aA, __fmul_rn(x2_, va.z));
                    aB = __fadd_rn(aB, __fmul_rn(x2_, vb.z));
                    aA = __fadd_rn(aA, __fmul_rn(x3, va.w));
                    aB = __fadd_rn(aB, __fmul_rn(x3, vb.w));
                }
                float dA = __fadd_rn(__fsub_rn(x2v, __fadd_rn(aA, aA)), e2g[ka]);
                float dB = __fadd_rn(__fsub_rn(x2v, __fadd_rn(aB, aB)), e2g[kb]);
                unsigned long long pa = ((unsigned long long)f2ord(dA) << 32) |
                                        (unsigned long long)(unsigned int)ka;
                unsigned long long pb = ((unsigned long long)f2ord(dB) << 32) |
                                        (unsigned long long)(unsigned int)kb;
                bb = (pa < bb) ? pa : bb;
                bb = (pb < bb) ? pb : bb;
            }
            if (j < c) {                   // tail single
                int k = list[(size_t)p * 192 + seg * CAP_SEG + j];
                const float4* er4 = (const float4*)(emb + (size_t)k * D);
                float acc = 0.f;
#pragma unroll 4
                for (int q = 0; q < D / 4; q++) {
                    float4 e4 = er4[q];
                    acc = __fadd_rn(acc, __fmul_rn(xs[q * 4 + 0][l], e4.x));
                    acc = __fadd_rn(acc, __fmul_rn(xs[q * 4 + 1][l], e4.y));
                    acc = __fadd_rn(acc, __fmul_rn(xs[q * 4 + 2][l], e4.z));
                    acc = __fadd_rn(acc, __fmul_rn(xs[q * 4 + 3][l], e4.w));
                }
                float dist = __fadd_rn(__fsub_rn(x2v, __fadd_rn(acc, acc)), e2g[k]);
                unsigned long long pk = ((unsigned long long)f2ord(dist) << 32) |
                                        (unsigned long long)(unsigned int)k;
                bb = (pk < bb) ? pk : bb;
            }
        }
    }
    bests[w][l] = bb;
    __syncthreads();

    if (tid < 32) {
        unsigned int cs2 = *(const unsigned int*)&cnt_seg[(size_t)(m0 + tid) * 4];
        bool ov2 = ((cs2 & 255) > CAP_SEG) | (((cs2 >> 8) & 255) > CAP_SEG) |
                   (((cs2 >> 16) & 255) > CAP_SEG) | (((cs2 >> 24) & 255) > CAP_SEG);
        if (!ov2) {
            unsigned long long v = bests[0][tid];
#pragma unroll
            for (int i = 1; i < 8; i++) v = (bests[i][tid] < v) ? bests[i][tid] : v;
            int kk = (int)(v & 0xFFFFFFFFull);
            ids[m0 + tid] = kk;
            kid_s[tid] = kk;
        } else {
            kid_s[tid] = -1;
        }
    }
    __syncthreads();

    // fused gather: ebuf aliases xs storage (32 rows x 65 floats)
    float* ebuf = &xs[0][0];
    float* outb = out + (size_t)b * D * T + t0;
    for (int d0 = 0; d0 < D; d0 += 64) {
        if (d0) __syncthreads();
#pragma unroll
        for (int i = 0; i < 8; i++) {          // read 32 rows x 64 d, coalesced
            int idx = tid + i * 256;
            int tt = idx >> 6, dd = idx & 63;
            int kk = kid_s[tt];
            ebuf[tt * 65 + dd] = emb[(size_t)(kk < 0 ? 0 : kk) * D + d0 + dd];
        }
        __syncthreads();
#pragma unroll
        for (int i = 0; i < 8; i++) {          // write transposed, 128B runs
            int idx = tid + i * 256;
            int tt = idx & 31, dd = idx >> 5;
            if (kid_s[tt] >= 0)
                outb[(size_t)(d0 + dd) * T + tt] = ebuf[tt * 65 + dd];
        }
    }
}

// ---- PARALLEL exact scan for overflow points (8 k-slices x blocks) -------
__global__ __launch_bounds__(256)
void vq_fallback_par(const float* __restrict__ lat, const float* __restrict__ emb,
                     const float* __restrict__ x2g, const float* __restrict__ e2g,
                     const int* __restrict__ ovfc, const int* __restrict__ ovfl,
                     unsigned long long* __restrict__ best) {
#pragma clang fp contract(off)
    __shared__ float xr[D];
    __shared__ unsigned long long wmin[4];
    const int n = *ovfc;
    const int ntask = n * 8;
    for (int task = blockIdx.x; task < ntask; task += gridDim.x) {
        const int m = ovfl[task >> 3];
        const int slice = task & 7;
        const int b = m / T, t = m % T;
        for (int d = threadIdx.x; d < D; d += 256)
            xr[d] = lat[(size_t)b * D * T + (size_t)d * T + t];
        __syncthreads();
        const float x2v = x2g[m];
        unsigned long long bl = ~0ull;
        for (int k = slice * 1024 + threadIdx.x; k < slice * 1024 + 1024; k += 256) {
            const float* er = emb + (size_t)k * D;
            float s = 0.f;
            for (int d = 0; d < D; d++)
                s = __fadd_rn(s, __fmul_rn(xr[d], er[d]));
            float tmp = __fsub_rn(x2v, __fadd_rn(s, s));
            float dist = __fadd_rn(tmp, e2g[k]);
            unsigned long long pk = ((unsigned long long)f2ord(dist) << 32) |
                                    (unsigned long long)(unsigned int)k;
            bl = (pk < bl) ? pk : bl;
        }
#pragma unroll
        for (int off = 1; off < 64; off <<= 1) {
            unsigned long long o = __shfl_xor(bl, off);
            bl = (o < bl) ? o : bl;
        }
        if ((threadIdx.x & 63) == 0) wmin[threadIdx.x >> 6] = bl;
        __syncthreads();
        if (threadIdx.x == 0) {
            unsigned long long v = wmin[0];
            for (int i = 1; i < 4; i++) v = (wmin[i] < v) ? wmin[i] : v;
            atomicMin(&best[m], v);
        }
        __syncthreads();
    }
}

// ---- gather + id-finalize for overflow points (rare; one block/point) ----
__global__ __launch_bounds__(256)
void vq_gather_ovf(const float* __restrict__ emb, const int* __restrict__ ovfc,
                   const int* __restrict__ ovfl,
                   const unsigned long long* __restrict__ best,
                   int* __restrict__ ids, float* __restrict__ out) {
    const int n = *ovfc;
    for (int i = blockIdx.x; i < n; i += gridDim.x) {
        int m = ovfl[i];
        int b = m / T, t = m % T;
        int k = (int)(best[m] & 0xFFFFFFFFull);
        if (threadIdx.x == 0) ids[m] = k;
        for (int d = threadIdx.x; d < D; d += 256)
            out[(size_t)b * D * T + (size_t)d * T + t] = emb[(size_t)k * D + d];
    }
}

// ================= round-3 validated fallback path (small ws) =============
#define TM 64
#define TN 128
#define TD 32
__global__ __launch_bounds__(256)
void vq_main_old(const float* __restrict__ latents, const float* __restrict__ emb,
                 const float* __restrict__ x2g, const float* __restrict__ e2g,
                 float* __restrict__ out) {
#pragma clang fp contract(off)
    __shared__ __align__(16) float xs[TD][TM];
    __shared__ __align__(16) float es[TD][TN + 4];
    __shared__ float e2s[TN];
    __shared__ float x2s[TM];
    __shared__ int ids_s[TM];
    __shared__ __align__(16) float gbuf[64][65];
    const int tid = threadIdx.x;
    const int tn = tid & 15;
    const int tm = tid >> 4;
    const int m0 = blockIdx.x * TM;
    const int b = m0 / T;
    const int t0 = m0 % T;
    const float* lat = latents + (size_t)b * D * T + t0;
    if (tid < TM) x2s[tid] = x2g[m0 + tid];
    float minv[4];
    int mini[4];
#pragma unroll
    for (int i = 0; i < 4; i++) { minv[i] = 3.4e38f; mini[i] = 0; }
    for (int k0 = 0; k0 < K; k0 += TN) {
        __syncthreads();
        if (tid < TN) e2s[tid] = e2g[k0 + tid];
        float s[4][8];
#pragma unroll
        for (int i = 0; i < 4; i++)
#pragma unroll
            for (int j = 0; j < 8; j++) s[i][j] = 0.0f;
        for (int d0 = 0; d0 < D; d0 += TD) {
            if (d0) __syncthreads();
#pragma unroll
            for (int i = 0; i < 8; i++) {
                int idx = tid + i * 256;
                int dd = idx >> 6, tt = idx & 63;
                xs[dd][tt] = lat[(size_t)(d0 + dd) * T + tt];
            }
#pragma unroll
            for (int i = 0; i < 16; i++) {
                int idx = tid + i * 256;
                int nn = idx >> 5, dd = idx & 31;
                es[dd][nn] = emb[(size_t)(k0 + nn) * D + d0 + dd];
            }
            __syncthreads();
#pragma unroll
            for (int d = 0; d < TD; d++) {
                float4 xr = *(const float4*)&xs[d][tm * 4];
                float4 ea = *(const float4*)&es[d][tn * 4];
                float4 eb = *(const float4*)&es[d][64 + tn * 4];
                float xv[4] = {xr.x, xr.y, xr.z, xr.w};
                float ev[8] = {ea.x, ea.y, ea.z, ea.w, eb.x, eb.y, eb.z, eb.w};
#pragma unroll
                for (int i = 0; i < 4; i++)
#pragma unroll
                    for (int j = 0; j < 8; j++)
                        s[i][j] = __fadd_rn(s[i][j], __fmul_rn(xv[i], ev[j]));
            }
        }
#pragma unroll
        for (int i = 0; i < 4; i++) {
            float x2v = x2s[tm * 4 + i];
#pragma unroll
            for (int j = 0; j < 8; j++) {
                int col = (j < 4) ? (tn * 4 + j) : (64 + tn * 4 + (j - 4));
                float s2 = __fadd_rn(s[i][j], s[i][j]);
                float tmp = __fsub_rn(x2v, s2);
                float dist = __fadd_rn(tmp, e2s[col]);
                int kk = k0 + col;
                if (dist < minv[i]) { minv[i] = dist; mini[i] = kk; }
            }
        }
    }
#pragma unroll
    for (int i = 0; i < 4; i++) {
        float v1 = minv[i];
        int i1 = mini[i];
#pragma unroll
        for (int off = 1; off < 16; off <<= 1) {
            float ov = __shfl_xor(v1, off);
            int oi = __shfl_xor(i1, off);
            if (ov < v1 || (ov == v1 && oi < i1)) { v1 = ov; i1 = oi; }
        }
        if (tn == 0) ids_s[tm * 4 + i] = i1;
    }
    __syncthreads();
    float* outb = out + (size_t)b * D * T + t0;
    for (int d0 = 0; d0 < D; d0 += 64) {
        if (d0) __syncthreads();
#pragma unroll
        for (int i = 0; i < 16; i++) {
            int idx = tid + i * 256;
            int tt = idx >> 6, dd = idx & 63;
            gbuf[tt][dd] = emb[(size_t)ids_s[tt] * D + d0 + dd];
        }
        __syncthreads();
#pragma unroll
        for (int i = 0; i < 16; i++) {
            int idx = tid + i * 256;
            int dd = idx >> 6, tt = idx & 63;
            outb[(size_t)(d0 + dd) * T + tt] = gbuf[tt][dd];
        }
    }
}

extern "C" void kernel_launch(void* const* d_in, const int* in_sizes, int n_in,
                              void* d_out, int out_size, void* d_ws, size_t ws_size,
                              hipStream_t stream) {
    const float* latents = (const float*)d_in[0];
    const float* emb     = (const float*)d_in[1];
    float* out = (float*)d_out;
    char* ws = (char*)d_ws;
    float* x2g = (float*)(ws + WS_X2);
    float* e2g = (float*)(ws + WS_E2);

    if (ws_size < (size_t)WS_NEED) {   // validated round-3 path
        hipLaunchKernelGGL(vq_x2_kernel, dim3(M / 256), dim3(256), 0, stream, latents, x2g);
        hipLaunchKernelGGL(vq_e2_kernel, dim3(K / 256), dim3(256), 0, stream, emb, e2g);
        hipLaunchKernelGGL(vq_main_old, dim3(M / TM), dim3(256), 0, stream,
                           latents, emb, x2g, e2g, out);
        return;
    }

    unsigned char* cnt_seg = (unsigned char*)(ws + WS_CNT);
    int* ids = (int*)(ws + WS_IDS);
    int* ovfc = (int*)(ws + WS_OVFC);
    int* ovfl = (int*)(ws + WS_OVFL);
    unsigned long long* best = (unsigned long long*)(ws + WS_BEST);
    unsigned int* gmin = (unsigned int*)(ws + WS_GMIN);
    unsigned short* list = (unsigned short*)(ws + WS_LIST);
    unsigned short* Ax = (unsigned short*)(ws + WS_AX);
    unsigned short* Be = (unsigned short*)(ws + WS_BE);

    hipLaunchKernelGGL(vq_x2_init, dim3(M / 256), dim3(256), 0, stream,
                       latents, x2g, (unsigned int*)cnt_seg, ovfc, gmin);
    hipLaunchKernelGGL(vq_e2_kernel, dim3(K / 256), dim3(256), 0, stream, emb, e2g);
    hipLaunchKernelGGL(vq_prep_a, dim3(M / 64), dim3(256), 0, stream, latents, Ax);
    hipLaunchKernelGGL(vq_prep_b, dim3((K * D) / 1024), dim3(256), 0, stream, emb, Be);
    hipLaunchKernelGGL(vq_gemm, dim3(M / BMg, K / NCHUNK), dim3(256), 0, stream,
                       Ax, Be, e2g, gmin, cnt_seg, list);
    hipLaunchKernelGGL(vq_rescore3, dim3(M / 32), dim3(256), 0, stream,
                       latents, emb, x2g, e2g, cnt_seg, list, ids, ovfc, ovfl, best, out);
    hipLaunchKernelGGL(vq_fallback_par, dim3(512), dim3(256), 0, stream,
                       latents, emb, x2g, e2g, ovfc, ovfl, best);
    hipLaunchKernelGGL(vq_gather_ovf, dim3(128), dim3(256), 0, stream,
                       emb, ovfc, ovfl, best, ids, out);
}